// Round 1
// baseline (1242.628 us; speedup 1.0000x reference)
//
#include <hip/hip_runtime.h>
#include <hip/hip_bf16.h>
#include <math.h>

#define L_SEQ 2048
#define DMODEL 1024
#define DINNER 2048
#define DSTATE 16
#define DTRANK 64
#define NHID 4096
#define NC 64
#define LC 32

typedef __bf16 bf16_t;
typedef __bf16 bf16x4 __attribute__((ext_vector_type(4)));
typedef __bf16 bf16x8 __attribute__((ext_vector_type(8)));
typedef float f32x4 __attribute__((ext_vector_type(4)));

#define BM 128
#define BN 128
#define BK 32
#define LDT 40  // padded LDS row stride (bf16 elems): 80B, 16B-aligned rows, 2-way bank alias (free)

// ---------------------------------------------------------------------------
// Generic C = A(M,K) @ W(N,K)^T with fp32->bf16 conversion in staging.
// EPI: 0 none | 1 +bias | 2 relu(+bias) | 3 softplus(+bias) | 4 +add1 | 5 +bias+add1+add2
// ---------------------------------------------------------------------------
template <int EPI>
__global__ __launch_bounds__(256) void gemm_bt(
    const float* __restrict__ A, int lda,
    const float* __restrict__ W, int ldw,
    float* __restrict__ C, int ldc,
    int M, int N, int K,
    const float* __restrict__ bias,
    const float* __restrict__ add1,
    const float* __restrict__ add2)
{
    __shared__ bf16_t As[BM * LDT];
    __shared__ bf16_t Ws[BN * LDT];

    const int tid  = threadIdx.x;
    const int m0   = blockIdx.y * BM;
    const int n0   = blockIdx.x * BN;
    const int lane = tid & 63;
    const int wid  = tid >> 6;
    const int wr   = wid >> 1;   // wave row (0..1) -> 64 rows
    const int wc   = wid & 1;    // wave col (0..1) -> 64 cols
    const int quad = lane >> 4;
    const int lr   = lane & 15;

    f32x4 acc[4][4] = {};

    for (int k0 = 0; k0 < K; k0 += BK) {
        // stage A tile (BM x BK) and W tile (BN x BK) as bf16
        #pragma unroll
        for (int i = 0; i < 4; ++i) {
            int idx = tid + i * 256;          // 0..1023
            int row = idx >> 3;
            int cv  = (idx & 7) << 2;
            // A: M is always a multiple of 128 here, no row guard
            float4 va = *(const float4*)(A + (size_t)(m0 + row) * lda + (k0 + cv));
            bf16x4 ba;
            ba[0] = (bf16_t)va.x; ba[1] = (bf16_t)va.y;
            ba[2] = (bf16_t)va.z; ba[3] = (bf16_t)va.w;
            *(bf16x4*)&As[row * LDT + cv] = ba;

            int gn = n0 + row;
            float4 vw = make_float4(0.f, 0.f, 0.f, 0.f);
            if (gn < N) vw = *(const float4*)(W + (size_t)gn * ldw + (k0 + cv));
            bf16x4 bw;
            bw[0] = (bf16_t)vw.x; bw[1] = (bf16_t)vw.y;
            bw[2] = (bf16_t)vw.z; bw[3] = (bf16_t)vw.w;
            *(bf16x4*)&Ws[row * LDT + cv] = bw;
        }
        __syncthreads();

        bf16x8 af[4], bf_[4];
        #pragma unroll
        for (int i = 0; i < 4; ++i)
            af[i] = *(const bf16x8*)&As[(wr * 64 + i * 16 + lr) * LDT + quad * 8];
        #pragma unroll
        for (int j = 0; j < 4; ++j)
            bf_[j] = *(const bf16x8*)&Ws[(wc * 64 + j * 16 + lr) * LDT + quad * 8];
        #pragma unroll
        for (int i = 0; i < 4; ++i)
            #pragma unroll
            for (int j = 0; j < 4; ++j)
                acc[i][j] = __builtin_amdgcn_mfma_f32_16x16x32_bf16(af[i], bf_[j], acc[i][j], 0, 0, 0);
        __syncthreads();
    }

    // epilogue + store. D[m][n]: m = quad*4 + reg, n = lane&15 (per 16x16 tile)
    #pragma unroll
    for (int i = 0; i < 4; ++i) {
        int row0 = m0 + wr * 64 + i * 16 + quad * 4;
        #pragma unroll
        for (int j = 0; j < 4; ++j) {
            int col = n0 + wc * 64 + j * 16 + lr;
            if (col < N) {
                float bv = 0.f;
                if (EPI == 1 || EPI == 2 || EPI == 3 || EPI == 5) bv = bias[col];
                #pragma unroll
                for (int r = 0; r < 4; ++r) {
                    int row = row0 + r;
                    float v = acc[i][j][r];
                    if (EPI == 1) v += bv;
                    else if (EPI == 2) v = fmaxf(v + bv, 0.f);
                    else if (EPI == 3) {
                        float t = v + bv;
                        v = fmaxf(t, 0.f) + log1pf(__expf(-fabsf(t)));
                    } else if (EPI == 4) {
                        v += add1[(size_t)row * ldc + col];
                    } else if (EPI == 5) {
                        v += bv + add1[(size_t)row * ldc + col] + add2[(size_t)row * ldc + col];
                    }
                    C[(size_t)row * ldc + col] = v;
                }
            }
        }
    }
}

// ---------------------------------------------------------------------------
// Row layernorm: one block per row, D = 1024
// ---------------------------------------------------------------------------
__global__ __launch_bounds__(256) void ln_kernel(
    const float* __restrict__ x, const float* __restrict__ g,
    const float* __restrict__ b, float* __restrict__ out)
{
    const int row = blockIdx.x;
    const float* xr = x + (size_t)row * DMODEL;
    float v[4];
    float s = 0.f, sq = 0.f;
    #pragma unroll
    for (int i = 0; i < 4; ++i) {
        v[i] = xr[threadIdx.x + i * 256];
        s += v[i];
        sq += v[i] * v[i];
    }
    #pragma unroll
    for (int off = 32; off > 0; off >>= 1) {
        s  += __shfl_xor(s, off);
        sq += __shfl_xor(sq, off);
    }
    __shared__ float rs_[4], rq_[4];
    int w = threadIdx.x >> 6;
    if ((threadIdx.x & 63) == 0) { rs_[w] = s; rq_[w] = sq; }
    __syncthreads();
    s  = rs_[0] + rs_[1] + rs_[2] + rs_[3];
    sq = rq_[0] + rq_[1] + rq_[2] + rq_[3];
    float mu  = s * (1.f / DMODEL);
    float var = sq * (1.f / DMODEL) - mu * mu;
    float rsd = rsqrtf(var + 1e-5f);
    #pragma unroll
    for (int i = 0; i < 4; ++i) {
        int col = threadIdx.x + i * 256;
        out[(size_t)row * DMODEL + col] = (v[i] - mu) * rsd * g[col] + b[col];
    }
}

// ---------------------------------------------------------------------------
// Causal depthwise conv (k=4) + SiLU.  xm = xz[:, :DINNER] (row stride 2*DINNER)
// ---------------------------------------------------------------------------
__global__ __launch_bounds__(256) void conv_silu(
    const float* __restrict__ xz, const float* __restrict__ cw,
    const float* __restrict__ cb, float* __restrict__ xc)
{
    int gid = blockIdx.x * 256 + threadIdx.x;
    int c = gid & (DINNER - 1);
    int t = gid >> 11;
    float acc = cb[c];
    #pragma unroll
    for (int k = 0; k < 4; ++k) {
        int tt = t + k - 3;
        if (tt >= 0) acc += xz[(size_t)tt * (2 * DINNER) + c] * cw[c * 4 + k];
    }
    float sig = 1.f / (1.f + __expf(-acc));
    xc[gid] = acc * sig;
}

// ---------------------------------------------------------------------------
// Selective scan, chunked 3-pass. Chunk product of dA is exp(A * sum(delta)).
// ---------------------------------------------------------------------------
__global__ __launch_bounds__(256) void scan_pass1(
    const float* __restrict__ delta, const float* __restrict__ xc,
    const float* __restrict__ proj, const float* __restrict__ A_log,
    float* __restrict__ carryH, float* __restrict__ sumd)
{
    const int c = blockIdx.x;
    const int d = blockIdx.y * 256 + threadIdx.x;
    const int t0 = c * LC;

    __shared__ float Bs[LC][DSTATE];
    for (int i = threadIdx.x; i < LC * DSTATE; i += 256) {
        int tt = i >> 4, s = i & 15;
        Bs[tt][s] = proj[(size_t)(t0 + tt) * 96 + DTRANK + s];
    }
    __syncthreads();

    float a[DSTATE], h[DSTATE];
    #pragma unroll
    for (int s = 0; s < DSTATE; ++s) {
        a[s] = -__expf(A_log[d * DSTATE + s]);
        h[s] = 0.f;
    }
    float sd = 0.f;
    for (int i = 0; i < LC; ++i) {
        int t = t0 + i;
        float dl = delta[(size_t)t * DINNER + d];
        float x  = xc[(size_t)t * DINNER + d];
        sd += dl;
        float dx = dl * x;
        #pragma unroll
        for (int s = 0; s < DSTATE; ++s)
            h[s] = h[s] * __expf(dl * a[s]) + dx * Bs[i][s];
    }
    #pragma unroll
    for (int s = 0; s < DSTATE; ++s)
        carryH[((size_t)c * DINNER + d) * DSTATE + s] = h[s];
    sumd[c * DINNER + d] = sd;
}

__global__ __launch_bounds__(256) void scan_pass2(
    const float* __restrict__ A_log, const float* __restrict__ carryH,
    const float* __restrict__ sumd, float* __restrict__ hinit)
{
    int idx = blockIdx.x * 256 + threadIdx.x;   // (d,s): 32768
    int d = idx >> 4;
    float a = -__expf(A_log[idx]);
    float hc = 0.f;
    for (int c = 0; c < NC; ++c) {
        hinit[(size_t)c * (DINNER * DSTATE) + idx] = hc;
        float P = __expf(a * sumd[c * DINNER + d]);
        hc = carryH[(size_t)c * (DINNER * DSTATE) + idx] + P * hc;
    }
}

__global__ __launch_bounds__(256) void scan_pass3(
    const float* __restrict__ delta, const float* __restrict__ xc,
    const float* __restrict__ proj, const float* __restrict__ A_log,
    const float* __restrict__ hinit, const float* __restrict__ Dp,
    const float* __restrict__ xz, float* __restrict__ yact)
{
    const int c = blockIdx.x;
    const int d = blockIdx.y * 256 + threadIdx.x;
    const int t0 = c * LC;

    __shared__ float Bs[LC][DSTATE], Cs[LC][DSTATE];
    for (int i = threadIdx.x; i < LC * DSTATE; i += 256) {
        int tt = i >> 4, s = i & 15;
        size_t base = (size_t)(t0 + tt) * 96;
        Bs[tt][s] = proj[base + DTRANK + s];
        Cs[tt][s] = proj[base + DTRANK + DSTATE + s];
    }
    __syncthreads();

    float a[DSTATE], h[DSTATE];
    #pragma unroll
    for (int s = 0; s < DSTATE; ++s) {
        a[s] = -__expf(A_log[d * DSTATE + s]);
        h[s] = hinit[(size_t)c * (DINNER * DSTATE) + d * DSTATE + s];
    }
    float DD = Dp[d];
    for (int i = 0; i < LC; ++i) {
        int t = t0 + i;
        float dl = delta[(size_t)t * DINNER + d];
        float x  = xc[(size_t)t * DINNER + d];
        float dx = dl * x;
        float y = 0.f;
        #pragma unroll
        for (int s = 0; s < DSTATE; ++s) {
            h[s] = h[s] * __expf(dl * a[s]) + dx * Bs[i][s];
            y += h[s] * Cs[i][s];
        }
        float yv = y + x * DD;
        float z = xz[(size_t)t * (2 * DINNER) + DINNER + d];
        float sil = z / (1.f + __expf(-z));
        yact[(size_t)t * DINNER + d] = yv * sil;
    }
}

// ---------------------------------------------------------------------------
extern "C" void kernel_launch(void* const* d_in, const int* in_sizes, int n_in,
                              void* d_out, int out_size, void* d_ws, size_t ws_size,
                              hipStream_t stream)
{
    const float* x        = (const float*)d_in[0];
    const float* ln1_g    = (const float*)d_in[1];
    const float* ln1_b    = (const float*)d_in[2];
    const float* ln2_g    = (const float*)d_in[3];
    const float* ln2_b    = (const float*)d_in[4];
    const float* in_proj  = (const float*)d_in[5];
    const float* conv_w   = (const float*)d_in[6];
    const float* conv_b   = (const float*)d_in[7];
    const float* x_proj   = (const float*)d_in[8];
    const float* dt_proj  = (const float*)d_in[9];
    const float* dt_b     = (const float*)d_in[10];
    const float* A_log    = (const float*)d_in[11];
    const float* D_param  = (const float*)d_in[12];
    const float* out_proj = (const float*)d_in[13];
    const float* ffn_w1   = (const float*)d_in[14];
    const float* ffn_b1   = (const float*)d_in[15];
    const float* ffn_w2   = (const float*)d_in[16];
    const float* ffn_b2   = (const float*)d_in[17];
    float* out = (float*)d_out;

    // workspace layout (floats); aliases: hres=h1, nbuf=carry, ffnh=xz
    float* ws    = (float*)d_ws;
    float* h1    = ws;                         // 2M
    float* xz    = h1 + (2u << 20);            // 8M
    float* xc    = xz + (8u << 20);            // 4M
    float* proj  = xc + (4u << 20);            // 196608
    float* delta = proj + 196608;              // 4M
    float* carry = delta + (4u << 20);         // 2M
    float* sumd  = carry + (2u << 20);         // 131072
    float* hinit = sumd + 131072;              // 2M
    float* yact  = hinit + (2u << 20);         // 4M
    float* hres  = h1;
    float* nbuf  = carry;
    float* ffnh  = xz;

    // 1. LN1
    ln_kernel<<<L_SEQ, 256, 0, stream>>>(x, ln1_g, ln1_b, h1);
    // 2. xz = h1 @ in_proj^T            (2048 x 4096 x 1024)
    gemm_bt<0><<<dim3(4096 / BN, L_SEQ / BM), 256, 0, stream>>>(
        h1, DMODEL, in_proj, DMODEL, xz, 2 * DINNER, L_SEQ, 2 * DINNER, DMODEL,
        nullptr, nullptr, nullptr);
    // 3. conv + silu -> xc
    conv_silu<<<(L_SEQ * DINNER) / 256, 256, 0, stream>>>(xz, conv_w, conv_b, xc);
    // 4. proj = xc @ x_proj^T           (2048 x 96 x 2048)
    gemm_bt<0><<<dim3(1, L_SEQ / BM), 256, 0, stream>>>(
        xc, DINNER, x_proj, DINNER, proj, 96, L_SEQ, 96, DINNER,
        nullptr, nullptr, nullptr);
    // 5. delta = softplus(dt @ dt_proj^T + b)   (2048 x 2048 x 64)
    gemm_bt<3><<<dim3(DINNER / BN, L_SEQ / BM), 256, 0, stream>>>(
        proj, 96, dt_proj, DTRANK, delta, DINNER, L_SEQ, DINNER, DTRANK,
        dt_b, nullptr, nullptr);
    // 6-8. scan
    scan_pass1<<<dim3(NC, DINNER / 256), 256, 0, stream>>>(delta, xc, proj, A_log, carry, sumd);
    scan_pass2<<<(DINNER * DSTATE) / 256, 256, 0, stream>>>(A_log, carry, sumd, hinit);
    scan_pass3<<<dim3(NC, DINNER / 256), 256, 0, stream>>>(delta, xc, proj, A_log, hinit, D_param, xz, yact);
    // 9. hres = yact @ out_proj^T + x   (2048 x 1024 x 2048)
    gemm_bt<4><<<dim3(DMODEL / BN, L_SEQ / BM), 256, 0, stream>>>(
        yact, DINNER, out_proj, DINNER, hres, DMODEL, L_SEQ, DMODEL, DINNER,
        nullptr, x, nullptr);
    // 10. LN2
    ln_kernel<<<L_SEQ, 256, 0, stream>>>(hres, ln2_g, ln2_b, nbuf);
    // 11. ffnh = relu(nbuf @ w1^T + b1) (2048 x 4096 x 1024)
    gemm_bt<2><<<dim3(NHID / BN, L_SEQ / BM), 256, 0, stream>>>(
        nbuf, DMODEL, ffn_w1, DMODEL, ffnh, NHID, L_SEQ, NHID, DMODEL,
        ffn_b1, nullptr, nullptr);
    // 12. out = ffnh @ w2^T + b2 + hres + nbuf   (2048 x 1024 x 4096)
    gemm_bt<5><<<dim3(DMODEL / BN, L_SEQ / BM), 256, 0, stream>>>(
        ffnh, NHID, ffn_w2, NHID, out, DMODEL, L_SEQ, DMODEL, NHID,
        ffn_b2, hres, nbuf);
}

// Round 2
// 410.316 us; speedup vs baseline: 3.0285x; 3.0285x over previous
//
#include <hip/hip_runtime.h>
#include <hip/hip_bf16.h>
#include <math.h>

#define L_SEQ 2048
#define DMODEL 1024
#define DINNER 2048
#define DSTATE 16
#define DTRANK 64
#define NHID 4096
#define NC 64
#define LC 32

typedef __bf16 bf16_t;
typedef __bf16 bf16x4 __attribute__((ext_vector_type(4)));
typedef __bf16 bf16x8 __attribute__((ext_vector_type(8)));
typedef float f32x4 __attribute__((ext_vector_type(4)));

// ---------------------------------------------------------------------------
// async 16B global->LDS
// ---------------------------------------------------------------------------
__device__ __forceinline__ void async_cp16(const bf16_t* g, bf16_t* l) {
    __builtin_amdgcn_global_load_lds(
        (const __attribute__((address_space(1))) void*)g,
        (__attribute__((address_space(3))) void*)l, 16, 0, 0);
}

// ---------------------------------------------------------------------------
// C = A(M,K)bf16 @ W(N,K)bf16^T, 128x128 tile, m97-style direct-to-LDS staging.
// LDS tile: row-major 128x32 bf16, 64B rows, chunk swizzle: data chunk dc of
// row r stored at position (dc + ((r>>1)&3)) & 3  (16B chunks) -> 2-way-only
// bank aliasing on both the lds-write and the ds_read_b128 side.
// EPI: 0 none | 2 relu+bias | 3 softplus+bias.  OUTBF16: store bf16 vs fp32.
// split-K: gridDim.z slices of Kslice; C += z*cstride (partials, EPI 0 only).
// ---------------------------------------------------------------------------
template <int EPI, int OUTBF16>
__global__ __launch_bounds__(256) void gemm_async(
    const bf16_t* __restrict__ A, int lda,
    const bf16_t* __restrict__ W, int ldw,
    void* __restrict__ Cv, int ldc,
    int N, int Kslice, long cstride,
    const float* __restrict__ bias)
{
    __shared__ bf16_t As[128 * 32];
    __shared__ bf16_t Ws[128 * 32];

    const int tid  = threadIdx.x;
    const int lane = tid & 63;
    const int w    = tid >> 6;
    const int m0   = blockIdx.y * 128;
    const int n0   = blockIdx.x * 128;
    const int kz   = blockIdx.z;
    const int k0   = kz * Kslice;

    // ---- staging addresses: wave w stages chunks {2w,2w+1} of A and W.
    // chunk c = rows [16c,16c+16), 1024B; lane i -> row 16c+(i>>2), pos i&3.
    const int p   = lane & 3;
    const int r0  = 2 * w * 16 + (lane >> 2);
    const int r1  = r0 + 16;
    const int dc0 = (p - ((r0 >> 1) & 3)) & 3;
    const int dc1 = (p - ((r1 >> 1) & 3)) & 3;

    const bf16_t* gA0 = A + (size_t)(m0 + r0) * lda + k0 + dc0 * 8;
    const bf16_t* gA1 = A + (size_t)(m0 + r1) * lda + k0 + dc1 * 8;
    int gn0 = n0 + r0; if (gn0 > N - 1) gn0 = N - 1;
    int gn1 = n0 + r1; if (gn1 > N - 1) gn1 = N - 1;
    const bf16_t* gW0 = W + (size_t)gn0 * ldw + k0 + dc0 * 8;
    const bf16_t* gW1 = W + (size_t)gn1 * ldw + k0 + dc1 * 8;
    bf16_t* lA0 = &As[(2 * w) * 512];
    bf16_t* lA1 = &As[(2 * w) * 512 + 512];
    bf16_t* lW0 = &Ws[(2 * w) * 512];
    bf16_t* lW1 = &Ws[(2 * w) * 512 + 512];

    // ---- fragment read offsets (constant per lane)
    const int wr   = w >> 1;
    const int wc   = w & 1;
    const int quad = lane >> 4;
    const int lr   = lane & 15;
    int offA[4], offW[4];
    #pragma unroll
    for (int i = 0; i < 4; ++i) {
        int ra = wr * 64 + i * 16 + lr;
        offA[i] = ra * 32 + (((quad + ((ra >> 1) & 3)) & 3) * 8);
        int rb = wc * 64 + i * 16 + lr;
        offW[i] = rb * 32 + (((quad + ((rb >> 1) & 3)) & 3) * 8);
    }

    f32x4 acc[4][4] = {};
    const int niter = Kslice >> 5;
    for (int it = 0; it < niter; ++it) {
        async_cp16(gA0, lA0);
        async_cp16(gA1, lA1);
        async_cp16(gW0, lW0);
        async_cp16(gW1, lW1);
        gA0 += 32; gA1 += 32; gW0 += 32; gW1 += 32;
        __builtin_amdgcn_s_waitcnt(0);
        __syncthreads();

        bf16x8 af[4], bw[4];
        #pragma unroll
        for (int i = 0; i < 4; ++i) af[i] = *(const bf16x8*)&As[offA[i]];
        #pragma unroll
        for (int j = 0; j < 4; ++j) bw[j] = *(const bf16x8*)&Ws[offW[j]];
        #pragma unroll
        for (int i = 0; i < 4; ++i)
            #pragma unroll
            for (int j = 0; j < 4; ++j)
                acc[i][j] = __builtin_amdgcn_mfma_f32_16x16x32_bf16(af[i], bw[j], acc[i][j], 0, 0, 0);
        __syncthreads();
    }

    float* Cf   = (float*)Cv + (size_t)kz * cstride;
    bf16_t* Cb  = (bf16_t*)Cv;
    #pragma unroll
    for (int i = 0; i < 4; ++i) {
        int row0 = m0 + wr * 64 + i * 16 + quad * 4;
        #pragma unroll
        for (int j = 0; j < 4; ++j) {
            int col = n0 + wc * 64 + j * 16 + lr;
            if (col < N) {
                float bv = (EPI == 2 || EPI == 3) ? bias[col] : 0.f;
                #pragma unroll
                for (int r = 0; r < 4; ++r) {
                    float v = acc[i][j][r];
                    if (EPI == 2) v = fmaxf(v + bv, 0.f);
                    else if (EPI == 3) {
                        float t = v + bv;
                        v = fmaxf(t, 0.f) + log1pf(__expf(-fabsf(t)));
                    }
                    size_t o = (size_t)(row0 + r) * ldc + col;
                    if (OUTBF16) Cb[o] = (bf16_t)v;
                    else         Cf[o] = v;
                }
            }
        }
    }
}

// ---------------------------------------------------------------------------
// weights fp32 -> bf16, one kernel, hardcoded segment table
// ---------------------------------------------------------------------------
__global__ __launch_bounds__(256) void cvt_weights(
    const float* __restrict__ s0, const float* __restrict__ s1,
    const float* __restrict__ s2, const float* __restrict__ s3,
    const float* __restrict__ s4, const float* __restrict__ s5,
    bf16_t* __restrict__ dst)
{
    int e = (blockIdx.x * 256 + threadIdx.x) * 4;
    const float* src; int local;
    if      (e < 4194304)  { src = s0; local = e; }
    else if (e < 4390912)  { src = s1; local = e - 4194304; }
    else if (e < 4521984)  { src = s2; local = e - 4390912; }
    else if (e < 6619136)  { src = s3; local = e - 4521984; }
    else if (e < 10813440) { src = s4; local = e - 6619136; }
    else                   { src = s5; local = e - 10813440; }
    float4 v = *(const float4*)(src + local);
    bf16x4 o;
    o[0] = (bf16_t)v.x; o[1] = (bf16_t)v.y; o[2] = (bf16_t)v.z; o[3] = (bf16_t)v.w;
    *(bf16x4*)(dst + e) = o;
}

// ---------------------------------------------------------------------------
// layernorm; MODE 0: bf16 out only, MODE 1: fp32 + bf16 out
// ---------------------------------------------------------------------------
template <int MODE>
__global__ __launch_bounds__(256) void ln_kernel(
    const float* __restrict__ x, const float* __restrict__ g,
    const float* __restrict__ b, float* __restrict__ outf,
    bf16_t* __restrict__ outb)
{
    const int row = blockIdx.x;
    const float* xr = x + (size_t)row * DMODEL;
    float v[4];
    float s = 0.f, sq = 0.f;
    #pragma unroll
    for (int i = 0; i < 4; ++i) {
        v[i] = xr[threadIdx.x + i * 256];
        s += v[i]; sq += v[i] * v[i];
    }
    #pragma unroll
    for (int off = 32; off > 0; off >>= 1) {
        s += __shfl_xor(s, off); sq += __shfl_xor(sq, off);
    }
    __shared__ float rs_[4], rq_[4];
    int w = threadIdx.x >> 6;
    if ((threadIdx.x & 63) == 0) { rs_[w] = s; rq_[w] = sq; }
    __syncthreads();
    s  = rs_[0] + rs_[1] + rs_[2] + rs_[3];
    sq = rq_[0] + rq_[1] + rq_[2] + rq_[3];
    float mu  = s * (1.f / DMODEL);
    float var = sq * (1.f / DMODEL) - mu * mu;
    float rsd = rsqrtf(var + 1e-5f);
    #pragma unroll
    for (int i = 0; i < 4; ++i) {
        int col = threadIdx.x + i * 256;
        float o = (v[i] - mu) * rsd * g[col] + b[col];
        if (MODE == 1) outf[(size_t)row * DMODEL + col] = o;
        outb[(size_t)row * DMODEL + col] = (bf16_t)o;
    }
}

// ---------------------------------------------------------------------------
// conv(k=4 causal) + silu; xz bf16 (row stride 4096), out xc bf16
// ---------------------------------------------------------------------------
__global__ __launch_bounds__(256) void conv_silu(
    const bf16_t* __restrict__ xz, const float* __restrict__ cw,
    const float* __restrict__ cb, bf16_t* __restrict__ xc)
{
    int gid = blockIdx.x * 256 + threadIdx.x;
    int c = gid & (DINNER - 1);
    int t = gid >> 11;
    float acc = cb[c];
    #pragma unroll
    for (int k = 0; k < 4; ++k) {
        int tt = t + k - 3;
        if (tt >= 0) acc += (float)xz[(size_t)tt * (2 * DINNER) + c] * cw[c * 4 + k];
    }
    float sig = 1.f / (1.f + __expf(-acc));
    xc[gid] = (bf16_t)(acc * sig);
}

// ---------------------------------------------------------------------------
// selective scan, chunked 3-pass
// ---------------------------------------------------------------------------
__global__ __launch_bounds__(256) void scan_pass1(
    const float* __restrict__ delta, const bf16_t* __restrict__ xc,
    const float* __restrict__ proj, const float* __restrict__ A_log,
    float* __restrict__ carryH, float* __restrict__ sumd)
{
    const int c = blockIdx.x;
    const int d = blockIdx.y * 256 + threadIdx.x;
    const int t0 = c * LC;

    __shared__ float Bs[LC][DSTATE];
    for (int i = threadIdx.x; i < LC * DSTATE; i += 256) {
        int tt = i >> 4, s = i & 15;
        Bs[tt][s] = proj[(size_t)(t0 + tt) * 96 + DTRANK + s];
    }
    __syncthreads();

    float a[DSTATE], h[DSTATE];
    #pragma unroll
    for (int s = 0; s < DSTATE; ++s) {
        a[s] = -__expf(A_log[d * DSTATE + s]);
        h[s] = 0.f;
    }
    float sd = 0.f;
    for (int i = 0; i < LC; ++i) {
        int t = t0 + i;
        float dl = delta[(size_t)t * DINNER + d];
        float x  = (float)xc[(size_t)t * DINNER + d];
        sd += dl;
        float dx = dl * x;
        #pragma unroll
        for (int s = 0; s < DSTATE; ++s)
            h[s] = h[s] * __expf(dl * a[s]) + dx * Bs[i][s];
    }
    #pragma unroll
    for (int s = 0; s < DSTATE; ++s)
        carryH[((size_t)c * DINNER + d) * DSTATE + s] = h[s];
    sumd[c * DINNER + d] = sd;
}

__global__ __launch_bounds__(256) void scan_pass2(
    const float* __restrict__ A_log, const float* __restrict__ carryH,
    const float* __restrict__ sumd, float* __restrict__ hinit)
{
    int idx = blockIdx.x * 256 + threadIdx.x;
    int d = idx >> 4;
    float a = -__expf(A_log[idx]);
    float hc = 0.f;
    for (int c = 0; c < NC; ++c) {
        hinit[(size_t)c * (DINNER * DSTATE) + idx] = hc;
        float P = __expf(a * sumd[c * DINNER + d]);
        hc = carryH[(size_t)c * (DINNER * DSTATE) + idx] + P * hc;
    }
}

__global__ __launch_bounds__(256) void scan_pass3(
    const float* __restrict__ delta, const bf16_t* __restrict__ xc,
    const float* __restrict__ proj, const float* __restrict__ A_log,
    const float* __restrict__ hinit, const float* __restrict__ Dp,
    const bf16_t* __restrict__ xz, bf16_t* __restrict__ yact)
{
    const int c = blockIdx.x;
    const int d = blockIdx.y * 256 + threadIdx.x;
    const int t0 = c * LC;

    __shared__ float Bs[LC][DSTATE], Cs[LC][DSTATE];
    for (int i = threadIdx.x; i < LC * DSTATE; i += 256) {
        int tt = i >> 4, s = i & 15;
        size_t base = (size_t)(t0 + tt) * 96;
        Bs[tt][s] = proj[base + DTRANK + s];
        Cs[tt][s] = proj[base + DTRANK + DSTATE + s];
    }
    __syncthreads();

    float a[DSTATE], h[DSTATE];
    #pragma unroll
    for (int s = 0; s < DSTATE; ++s) {
        a[s] = -__expf(A_log[d * DSTATE + s]);
        h[s] = hinit[(size_t)c * (DINNER * DSTATE) + d * DSTATE + s];
    }
    float DD = Dp[d];
    for (int i = 0; i < LC; ++i) {
        int t = t0 + i;
        float dl = delta[(size_t)t * DINNER + d];
        float x  = (float)xc[(size_t)t * DINNER + d];
        float dx = dl * x;
        float y = 0.f;
        #pragma unroll
        for (int s = 0; s < DSTATE; ++s) {
            h[s] = h[s] * __expf(dl * a[s]) + dx * Bs[i][s];
            y += h[s] * Cs[i][s];
        }
        float yv = y + x * DD;
        float z = (float)xz[(size_t)t * (2 * DINNER) + DINNER + d];
        float sil = z / (1.f + __expf(-z));
        yact[(size_t)t * DINNER + d] = (bf16_t)(yv * sil);
    }
}

// ---------------------------------------------------------------------------
// split-K reduces
// ---------------------------------------------------------------------------
__global__ __launch_bounds__(256) void reduce4(
    const float* __restrict__ part, float* __restrict__ proj,
    bf16_t* __restrict__ projdt)
{
    int i = blockIdx.x * 256 + threadIdx.x;      // 196608
    float v = 0.f;
    #pragma unroll
    for (int s = 0; s < 16; ++s) v += part[(size_t)s * 196608 + i];
    proj[i] = v;
    int row = i / 96;
    int col = i - row * 96;
    if (col < DTRANK) projdt[row * DTRANK + col] = (bf16_t)v;
}

__global__ __launch_bounds__(256) void reduce9(
    const float* __restrict__ part, const float* __restrict__ x,
    float* __restrict__ hres)
{
    int i = (blockIdx.x * 256 + threadIdx.x) * 4;
    float4 a = *(const float4*)(part + i);
    float4 b = *(const float4*)(part + 2097152 + i);
    float4 c = *(const float4*)(x + i);
    float4 o = make_float4(a.x + b.x + c.x, a.y + b.y + c.y,
                           a.z + b.z + c.z, a.w + b.w + c.w);
    *(float4*)(hres + i) = o;
}

__global__ __launch_bounds__(256) void reduce12(
    const float* __restrict__ part, const float* __restrict__ b2,
    const float* __restrict__ hres, const float* __restrict__ nbuf,
    float* __restrict__ out)
{
    int i = (blockIdx.x * 256 + threadIdx.x) * 4;
    float4 a = *(const float4*)(part + i);
    float4 b = *(const float4*)(part + 2097152 + i);
    float4 bb = *(const float4*)(b2 + (i & (DMODEL - 1)));
    float4 h = *(const float4*)(hres + i);
    float4 n = *(const float4*)(nbuf + i);
    float4 o = make_float4(a.x + b.x + bb.x + h.x + n.x,
                           a.y + b.y + bb.y + h.y + n.y,
                           a.z + b.z + bb.z + h.z + n.z,
                           a.w + b.w + bb.w + h.w + n.w);
    *(float4*)(out + i) = o;
}

// ---------------------------------------------------------------------------
extern "C" void kernel_launch(void* const* d_in, const int* in_sizes, int n_in,
                              void* d_out, int out_size, void* d_ws, size_t ws_size,
                              hipStream_t stream)
{
    const float* x        = (const float*)d_in[0];
    const float* ln1_g    = (const float*)d_in[1];
    const float* ln1_b    = (const float*)d_in[2];
    const float* ln2_g    = (const float*)d_in[3];
    const float* ln2_b    = (const float*)d_in[4];
    const float* in_proj  = (const float*)d_in[5];
    const float* conv_w   = (const float*)d_in[6];
    const float* conv_b   = (const float*)d_in[7];
    const float* x_proj   = (const float*)d_in[8];
    const float* dt_proj  = (const float*)d_in[9];
    const float* dt_b     = (const float*)d_in[10];
    const float* A_log    = (const float*)d_in[11];
    const float* D_param  = (const float*)d_in[12];
    const float* out_proj = (const float*)d_in[13];
    const float* ffn_w1   = (const float*)d_in[14];
    const float* ffn_b1   = (const float*)d_in[15];
    const float* ffn_w2   = (const float*)d_in[16];
    const float* ffn_b2   = (const float*)d_in[17];
    float* out = (float*)d_out;

    // ---- ws layout (bytes), aggressive aliasing
    char* base = (char*)d_ws;
    bf16_t* Wb     = (bf16_t*)(base);                    // 30,015,488 B
    bf16_t* w_inp  = Wb;                                  // 4194304 el
    bf16_t* w_xp   = Wb + 4194304;                        // 196608
    bf16_t* w_dtp  = Wb + 4390912;                        // 131072
    bf16_t* w_outp = Wb + 4521984;                        // 2097152
    bf16_t* w_f1   = Wb + 6619136;                        // 4194304
    bf16_t* w_f2   = Wb + 10813440;                       // 4194304

    bf16_t* h1b    = (bf16_t*)(base + 30015488);          // 4 MB region
    float*  proj   = (float*)(base + 30015488);           // alias (after GEMM2)
    bf16_t* projdt = (bf16_t*)(base + 30015488 + 786432);
    bf16_t* xz     = (bf16_t*)(base + 34209792);          // 16 MB; ffnh later
    bf16_t* ffnh   = xz;
    bf16_t* xc     = (bf16_t*)(base + 50987008);          // 8 MB
    float*  part   = (float*)(base + 59375616);           // 16 MB: p4/p9/p12 + delta
    float*  delta  = part;                                //   (delta after reduce4)
    float*  carry  = (float*)(base + 76152832);           // 8 MB; nbufb later
    bf16_t* nbufb  = (bf16_t*)carry;
    float*  sumd   = (float*)(base + 84541440);           // 0.5 MB
    float*  hinit  = (float*)(base + 85065728);           // 8 MB; nbuf later
    float*  nbuf   = hinit;
    bf16_t* yact   = (bf16_t*)(base + 93454336);          // 8 MB
    float*  hres   = (float*)(base + 101842944);          // 8 MB
    // total 110,231,552 B

    // 0. weights -> bf16  (15,007,744 elems / 4 per thread / 256)
    cvt_weights<<<14656, 256, 0, stream>>>(in_proj, x_proj, dt_proj, out_proj,
                                           ffn_w1, ffn_w2, Wb);
    // 1. LN1 -> h1b (bf16)
    ln_kernel<0><<<L_SEQ, 256, 0, stream>>>(x, ln1_g, ln1_b, nullptr, h1b);
    // 2. xz = h1 @ in_proj^T   (2048x4096x1024) -> bf16
    gemm_async<0, 1><<<dim3(32, 16, 1), 256, 0, stream>>>(
        h1b, DMODEL, w_inp, DMODEL, xz, 4096, 4096, 1024, 0, nullptr);
    // 3. conv + silu -> xc (bf16)
    conv_silu<<<(L_SEQ * DINNER) / 256, 256, 0, stream>>>(xz, conv_w, conv_b, xc);
    // 4. proj partials = xc @ x_proj^T  (2048x96x2048, split-K 16)
    gemm_async<0, 0><<<dim3(1, 16, 16), 256, 0, stream>>>(
        xc, DINNER, w_xp, DINNER, part, 96, 96, 128, 196608L, nullptr);
    // 5. reduce -> proj fp32 + projdt bf16
    reduce4<<<768, 256, 0, stream>>>(part, proj, projdt);
    // 6. delta = softplus(dt @ dt_proj^T + b)  (2048x2048x64)
    gemm_async<3, 0><<<dim3(16, 16, 1), 256, 0, stream>>>(
        projdt, DTRANK, w_dtp, DTRANK, delta, DINNER, DINNER, DTRANK, 0, dt_b);
    // 7-9. scan
    scan_pass1<<<dim3(NC, DINNER / 256), 256, 0, stream>>>(delta, xc, proj, A_log, carry, sumd);
    scan_pass2<<<(DINNER * DSTATE) / 256, 256, 0, stream>>>(A_log, carry, sumd, hinit);
    scan_pass3<<<dim3(NC, DINNER / 256), 256, 0, stream>>>(delta, xc, proj, A_log, hinit,
                                                           D_param, xz, yact);
    // 10. out_proj partials (2048x1024x2048, split-K 2)
    gemm_async<0, 0><<<dim3(8, 16, 2), 256, 0, stream>>>(
        yact, DINNER, w_outp, DINNER, part, DMODEL, DMODEL, 1024, 2097152L, nullptr);
    // 11. hres = p0 + p1 + x
    reduce9<<<2048, 256, 0, stream>>>(part, x, hres);
    // 12. LN2 -> nbuf fp32 + nbufb bf16
    ln_kernel<1><<<L_SEQ, 256, 0, stream>>>(hres, ln2_g, ln2_b, nbuf, nbufb);
    // 13. ffnh = relu(nbuf @ w1^T + b1) -> bf16  (2048x4096x1024)
    gemm_async<2, 1><<<dim3(32, 16, 1), 256, 0, stream>>>(
        nbufb, DMODEL, w_f1, DMODEL, ffnh, NHID, NHID, 1024, 0, ffn_b1);
    // 14. ffn2 partials (2048x1024x4096, split-K 2)
    gemm_async<0, 0><<<dim3(8, 16, 2), 256, 0, stream>>>(
        ffnh, NHID, w_f2, NHID, part, DMODEL, DMODEL, 2048, 2097152L, nullptr);
    // 15. out = p0 + p1 + b2 + hres + nbuf
    reduce12<<<2048, 256, 0, stream>>>(part, ffn_b2, hres, nbuf, out);
}

// Round 3
// 379.059 us; speedup vs baseline: 3.2782x; 1.0825x over previous
//
#include <hip/hip_runtime.h>
#include <hip/hip_bf16.h>
#include <math.h>

#define L_SEQ 2048
#define DMODEL 1024
#define DINNER 2048
#define DSTATE 16
#define DTRANK 64
#define NHID 4096
#define NC 64
#define LC 32

typedef __bf16 bf16_t;
typedef __bf16 bf16x4 __attribute__((ext_vector_type(4)));
typedef __bf16 bf16x8 __attribute__((ext_vector_type(8)));
typedef float f32x4 __attribute__((ext_vector_type(4)));

// waitcnt imms: vmcnt(N) | expcnt=7 | lgkmcnt=15
#define WAIT_VM0 0x0F70
#define WAIT_VM4 0x0F74
#define WAIT_VM8 0x0F78

__device__ __forceinline__ void async_cp16(const bf16_t* g, bf16_t* l) {
    __builtin_amdgcn_global_load_lds(
        (const __attribute__((address_space(1))) void*)g,
        (__attribute__((address_space(3))) void*)l, 16, 0, 0);
}

// ---------------------------------------------------------------------------
// C = A(M,K)bf16 @ W(N,K)bf16^T, 128x128 tile, 4-stage software-pipelined
// global_load_lds staging with fine-grained vmcnt (loads stay in flight
// across the raw s_barrier). LDS tile per stage: row-major 128x32 bf16,
// 16B-chunk swizzle (dc + ((r>>1)&3))&3 -> 2-way-only bank aliasing (free).
// EPI: 0 none | 2 relu+bias | 3 softplus+bias.  OUTBF16: bf16 vs fp32 store.
// split-K: gridDim.z slices of Kslice; C += z*cstride (elements).
// ---------------------------------------------------------------------------
template <int EPI, int OUTBF16>
__global__ __launch_bounds__(256) void gemm_async(
    const bf16_t* __restrict__ A, int lda,
    const bf16_t* __restrict__ W, int ldw,
    void* __restrict__ Cv, int ldc,
    int N, int Kslice, long cstride,
    const float* __restrict__ bias)
{
    __shared__ bf16_t As[4 * 4096];
    __shared__ bf16_t Ws[4 * 4096];

    const int tid  = threadIdx.x;
    const int lane = tid & 63;
    const int w    = tid >> 6;
    const int m0   = blockIdx.y * 128;
    const int n0   = blockIdx.x * 128;
    const int kz   = blockIdx.z;
    const int k0   = kz * Kslice;

    // staging: wave w stages chunks {2w,2w+1} (rows 32w..32w+31) of A and W.
    const int p   = lane & 3;
    const int r0  = 2 * w * 16 + (lane >> 2);
    const int r1  = r0 + 16;
    const int dc0 = (p - ((r0 >> 1) & 3)) & 3;
    const int dc1 = (p - ((r1 >> 1) & 3)) & 3;

    const bf16_t* gA0 = A + (size_t)(m0 + r0) * lda + k0 + dc0 * 8;
    const bf16_t* gA1 = A + (size_t)(m0 + r1) * lda + k0 + dc1 * 8;
    int gn0 = n0 + r0; if (gn0 > N - 1) gn0 = N - 1;
    int gn1 = n0 + r1; if (gn1 > N - 1) gn1 = N - 1;
    const bf16_t* gW0 = W + (size_t)gn0 * ldw + k0 + dc0 * 8;
    const bf16_t* gW1 = W + (size_t)gn1 * ldw + k0 + dc1 * 8;

    const int lo0 = (2 * w) * 512;        // within-stage LDS offsets
    const int lo1 = lo0 + 512;

    // fragment read offsets (within stage)
    const int wr   = w >> 1;
    const int wc   = w & 1;
    const int quad = lane >> 4;
    const int lr   = lane & 15;
    int offA[4], offW[4];
    #pragma unroll
    for (int i = 0; i < 4; ++i) {
        int ra = wr * 64 + i * 16 + lr;
        offA[i] = ra * 32 + (((quad + ((ra >> 1) & 3)) & 3) * 8);
        int rb = wc * 64 + i * 16 + lr;
        offW[i] = rb * 32 + (((quad + ((rb >> 1) & 3)) & 3) * 8);
    }

    const int niter = Kslice >> 5;

    // prologue: issue iters 0..2 into stages 0..2
    #pragma unroll
    for (int j = 0; j < 3; ++j) {
        if (j < niter) {
            int sb = j * 4096;
            async_cp16(gA0, &As[sb + lo0]);
            async_cp16(gA1, &As[sb + lo1]);
            async_cp16(gW0, &Ws[sb + lo0]);
            async_cp16(gW1, &Ws[sb + lo1]);
            gA0 += 32; gA1 += 32; gW0 += 32; gW1 += 32;
        }
    }

    f32x4 acc[4][4] = {};
    for (int it = 0; it < niter; ++it) {
        // wait for iter-it's 4 loads (issued 3 iters ago) to land
        if (it + 3 <= niter)      __builtin_amdgcn_s_waitcnt(WAIT_VM8);
        else if (it + 2 <= niter) __builtin_amdgcn_s_waitcnt(WAIT_VM4);
        else                      __builtin_amdgcn_s_waitcnt(WAIT_VM0);
        __builtin_amdgcn_s_barrier();      // raw barrier: no vmcnt(0) drain
        asm volatile("" ::: "memory");

        // prefetch iter it+3 into stage (it+3)&3 (freed: consumed at it-1)
        if (it + 3 < niter) {
            int sb = ((it + 3) & 3) * 4096;
            async_cp16(gA0, &As[sb + lo0]);
            async_cp16(gA1, &As[sb + lo1]);
            async_cp16(gW0, &Ws[sb + lo0]);
            async_cp16(gW1, &Ws[sb + lo1]);
            gA0 += 32; gA1 += 32; gW0 += 32; gW1 += 32;
        }

        const int cb = (it & 3) * 4096;
        bf16x8 af[4], bw[4];
        #pragma unroll
        for (int i = 0; i < 4; ++i) af[i] = *(const bf16x8*)&As[cb + offA[i]];
        #pragma unroll
        for (int j = 0; j < 4; ++j) bw[j] = *(const bf16x8*)&Ws[cb + offW[j]];
        #pragma unroll
        for (int i = 0; i < 4; ++i)
            #pragma unroll
            for (int j = 0; j < 4; ++j)
                acc[i][j] = __builtin_amdgcn_mfma_f32_16x16x32_bf16(af[i], bw[j], acc[i][j], 0, 0, 0);
    }

    float*  Cf = (float*)Cv + (size_t)kz * cstride;
    bf16_t* Cb = (bf16_t*)Cv + (size_t)kz * cstride;
    #pragma unroll
    for (int i = 0; i < 4; ++i) {
        int row0 = m0 + wr * 64 + i * 16 + quad * 4;
        #pragma unroll
        for (int j = 0; j < 4; ++j) {
            int col = n0 + wc * 64 + j * 16 + lr;
            if (col < N) {
                float bv = (EPI == 2 || EPI == 3) ? bias[col] : 0.f;
                #pragma unroll
                for (int r = 0; r < 4; ++r) {
                    float v = acc[i][j][r];
                    if (EPI == 2) v = fmaxf(v + bv, 0.f);
                    else if (EPI == 3) {
                        float t = v + bv;
                        v = fmaxf(t, 0.f) + log1pf(__expf(-fabsf(t)));
                    }
                    size_t o = (size_t)(row0 + r) * ldc + col;
                    if (OUTBF16) Cb[o] = (bf16_t)v;
                    else         Cf[o] = v;
                }
            }
        }
    }
}

// ---------------------------------------------------------------------------
__global__ __launch_bounds__(256) void cvt_weights(
    const float* __restrict__ s0, const float* __restrict__ s1,
    const float* __restrict__ s2, const float* __restrict__ s3,
    const float* __restrict__ s4, const float* __restrict__ s5,
    bf16_t* __restrict__ dst)
{
    int e = (blockIdx.x * 256 + threadIdx.x) * 4;
    const float* src; int local;
    if      (e < 4194304)  { src = s0; local = e; }
    else if (e < 4390912)  { src = s1; local = e - 4194304; }
    else if (e < 4521984)  { src = s2; local = e - 4390912; }
    else if (e < 6619136)  { src = s3; local = e - 4521984; }
    else if (e < 10813440) { src = s4; local = e - 6619136; }
    else                   { src = s5; local = e - 10813440; }
    float4 v = *(const float4*)(src + local);
    bf16x4 o;
    o[0] = (bf16_t)v.x; o[1] = (bf16_t)v.y; o[2] = (bf16_t)v.z; o[3] = (bf16_t)v.w;
    *(bf16x4*)(dst + e) = o;
}

// ---------------------------------------------------------------------------
template <int MODE>
__global__ __launch_bounds__(256) void ln_kernel(
    const float* __restrict__ x, const float* __restrict__ g,
    const float* __restrict__ b, float* __restrict__ outf,
    bf16_t* __restrict__ outb)
{
    const int row = blockIdx.x;
    const float* xr = x + (size_t)row * DMODEL;
    float v[4];
    float s = 0.f, sq = 0.f;
    #pragma unroll
    for (int i = 0; i < 4; ++i) {
        v[i] = xr[threadIdx.x + i * 256];
        s += v[i]; sq += v[i] * v[i];
    }
    #pragma unroll
    for (int off = 32; off > 0; off >>= 1) {
        s += __shfl_xor(s, off); sq += __shfl_xor(sq, off);
    }
    __shared__ float rs_[4], rq_[4];
    int w = threadIdx.x >> 6;
    if ((threadIdx.x & 63) == 0) { rs_[w] = s; rq_[w] = sq; }
    __syncthreads();
    s  = rs_[0] + rs_[1] + rs_[2] + rs_[3];
    sq = rq_[0] + rq_[1] + rq_[2] + rq_[3];
    float mu  = s * (1.f / DMODEL);
    float var = sq * (1.f / DMODEL) - mu * mu;
    float rsd = rsqrtf(var + 1e-5f);
    #pragma unroll
    for (int i = 0; i < 4; ++i) {
        int col = threadIdx.x + i * 256;
        float o = (v[i] - mu) * rsd * g[col] + b[col];
        if (MODE == 1) outf[(size_t)row * DMODEL + col] = o;
        outb[(size_t)row * DMODEL + col] = (bf16_t)o;
    }
}

// ---------------------------------------------------------------------------
__global__ __launch_bounds__(256) void conv_silu(
    const bf16_t* __restrict__ xz, const float* __restrict__ cw,
    const float* __restrict__ cb, bf16_t* __restrict__ xc)
{
    int gid = blockIdx.x * 256 + threadIdx.x;
    int c = gid & (DINNER - 1);
    int t = gid >> 11;
    float acc = cb[c];
    #pragma unroll
    for (int k = 0; k < 4; ++k) {
        int tt = t + k - 3;
        if (tt >= 0) acc += (float)xz[(size_t)tt * (2 * DINNER) + c] * cw[c * 4 + k];
    }
    float sig = 1.f / (1.f + __expf(-acc));
    xc[gid] = (bf16_t)(acc * sig);
}

// ---------------------------------------------------------------------------
__global__ __launch_bounds__(256) void scan_pass1(
    const float* __restrict__ delta, const bf16_t* __restrict__ xc,
    const float* __restrict__ proj, const float* __restrict__ A_log,
    float* __restrict__ carryH, float* __restrict__ sumd)
{
    const int c = blockIdx.x;
    const int d = blockIdx.y * 256 + threadIdx.x;
    const int t0 = c * LC;

    __shared__ float Bs[LC][DSTATE];
    for (int i = threadIdx.x; i < LC * DSTATE; i += 256) {
        int tt = i >> 4, s = i & 15;
        Bs[tt][s] = proj[(size_t)(t0 + tt) * 96 + DTRANK + s];
    }
    __syncthreads();

    float a[DSTATE], h[DSTATE];
    #pragma unroll
    for (int s = 0; s < DSTATE; ++s) {
        a[s] = -__expf(A_log[d * DSTATE + s]);
        h[s] = 0.f;
    }
    float sd = 0.f;
    for (int i = 0; i < LC; ++i) {
        int t = t0 + i;
        float dl = delta[(size_t)t * DINNER + d];
        float x  = (float)xc[(size_t)t * DINNER + d];
        sd += dl;
        float dx = dl * x;
        #pragma unroll
        for (int s = 0; s < DSTATE; ++s)
            h[s] = h[s] * __expf(dl * a[s]) + dx * Bs[i][s];
    }
    #pragma unroll
    for (int s = 0; s < DSTATE; ++s)
        carryH[((size_t)c * DINNER + d) * DSTATE + s] = h[s];
    sumd[c * DINNER + d] = sd;
}

__global__ __launch_bounds__(256) void scan_pass2(
    const float* __restrict__ A_log, const float* __restrict__ carryH,
    const float* __restrict__ sumd, float* __restrict__ hinit)
{
    int idx = blockIdx.x * 256 + threadIdx.x;
    int d = idx >> 4;
    float a = -__expf(A_log[idx]);
    float hc = 0.f;
    for (int c = 0; c < NC; ++c) {
        hinit[(size_t)c * (DINNER * DSTATE) + idx] = hc;
        float P = __expf(a * sumd[c * DINNER + d]);
        hc = carryH[(size_t)c * (DINNER * DSTATE) + idx] + P * hc;
    }
}

__global__ __launch_bounds__(256) void scan_pass3(
    const float* __restrict__ delta, const bf16_t* __restrict__ xc,
    const float* __restrict__ proj, const float* __restrict__ A_log,
    const float* __restrict__ hinit, const float* __restrict__ Dp,
    const bf16_t* __restrict__ xz, bf16_t* __restrict__ yact)
{
    const int c = blockIdx.x;
    const int d = blockIdx.y * 256 + threadIdx.x;
    const int t0 = c * LC;

    __shared__ float Bs[LC][DSTATE], Cs[LC][DSTATE];
    for (int i = threadIdx.x; i < LC * DSTATE; i += 256) {
        int tt = i >> 4, s = i & 15;
        size_t base = (size_t)(t0 + tt) * 96;
        Bs[tt][s] = proj[base + DTRANK + s];
        Cs[tt][s] = proj[base + DTRANK + DSTATE + s];
    }
    __syncthreads();

    float a[DSTATE], h[DSTATE];
    #pragma unroll
    for (int s = 0; s < DSTATE; ++s) {
        a[s] = -__expf(A_log[d * DSTATE + s]);
        h[s] = hinit[(size_t)c * (DINNER * DSTATE) + d * DSTATE + s];
    }
    float DD = Dp[d];
    for (int i = 0; i < LC; ++i) {
        int t = t0 + i;
        float dl = delta[(size_t)t * DINNER + d];
        float x  = (float)xc[(size_t)t * DINNER + d];
        float dx = dl * x;
        float y = 0.f;
        #pragma unroll
        for (int s = 0; s < DSTATE; ++s) {
            h[s] = h[s] * __expf(dl * a[s]) + dx * Bs[i][s];
            y += h[s] * Cs[i][s];
        }
        float yv = y + x * DD;
        float z = (float)xz[(size_t)t * (2 * DINNER) + DINNER + d];
        float sil = z / (1.f + __expf(-z));
        yact[(size_t)t * DINNER + d] = (bf16_t)(yv * sil);
    }
}

// ---------------------------------------------------------------------------
// split-K reduces
// ---------------------------------------------------------------------------
__global__ __launch_bounds__(256) void reduce4(
    const float* __restrict__ part, float* __restrict__ proj,
    bf16_t* __restrict__ projdt)
{
    int i = blockIdx.x * 256 + threadIdx.x;      // 196608
    float v = 0.f;
    #pragma unroll
    for (int s = 0; s < 16; ++s) v += part[(size_t)s * 196608 + i];
    proj[i] = v;
    int row = i / 96;
    int col = i - row * 96;
    if (col < DTRANK) projdt[row * DTRANK + col] = (bf16_t)v;
}

__global__ __launch_bounds__(256) void reduce9(
    const bf16_t* __restrict__ part, const float* __restrict__ x,
    float* __restrict__ hres)
{
    int i = (blockIdx.x * 256 + threadIdx.x) * 4;
    float4 c = *(const float4*)(x + i);
    float s0 = c.x, s1 = c.y, s2 = c.z, s3 = c.w;
    #pragma unroll
    for (int sl = 0; sl < 4; ++sl) {
        bf16x4 v = *(const bf16x4*)(part + (size_t)sl * 2097152 + i);
        s0 += (float)v[0]; s1 += (float)v[1]; s2 += (float)v[2]; s3 += (float)v[3];
    }
    *(float4*)(hres + i) = make_float4(s0, s1, s2, s3);
}

__global__ __launch_bounds__(256) void reduce12(
    const bf16_t* __restrict__ part, const float* __restrict__ b2,
    const float* __restrict__ hres, const float* __restrict__ nbuf,
    float* __restrict__ out)
{
    int i = (blockIdx.x * 256 + threadIdx.x) * 4;
    float4 bb = *(const float4*)(b2 + (i & (DMODEL - 1)));
    float4 h  = *(const float4*)(hres + i);
    float4 n  = *(const float4*)(nbuf + i);
    float s0 = bb.x + h.x + n.x, s1 = bb.y + h.y + n.y;
    float s2 = bb.z + h.z + n.z, s3 = bb.w + h.w + n.w;
    #pragma unroll
    for (int sl = 0; sl < 4; ++sl) {
        bf16x4 v = *(const bf16x4*)(part + (size_t)sl * 2097152 + i);
        s0 += (float)v[0]; s1 += (float)v[1]; s2 += (float)v[2]; s3 += (float)v[3];
    }
    *(float4*)(out + i) = make_float4(s0, s1, s2, s3);
}

// ---------------------------------------------------------------------------
extern "C" void kernel_launch(void* const* d_in, const int* in_sizes, int n_in,
                              void* d_out, int out_size, void* d_ws, size_t ws_size,
                              hipStream_t stream)
{
    const float* x        = (const float*)d_in[0];
    const float* ln1_g    = (const float*)d_in[1];
    const float* ln1_b    = (const float*)d_in[2];
    const float* ln2_g    = (const float*)d_in[3];
    const float* ln2_b    = (const float*)d_in[4];
    const float* in_proj  = (const float*)d_in[5];
    const float* conv_w   = (const float*)d_in[6];
    const float* conv_b   = (const float*)d_in[7];
    const float* x_proj   = (const float*)d_in[8];
    const float* dt_proj  = (const float*)d_in[9];
    const float* dt_b     = (const float*)d_in[10];
    const float* A_log    = (const float*)d_in[11];
    const float* D_param  = (const float*)d_in[12];
    const float* out_proj = (const float*)d_in[13];
    const float* ffn_w1   = (const float*)d_in[14];
    const float* ffn_b1   = (const float*)d_in[15];
    const float* ffn_w2   = (const float*)d_in[16];
    const float* ffn_b2   = (const float*)d_in[17];
    float* out = (float*)d_out;

    // ---- ws layout (identical footprint to R2: 110,231,552 B)
    char* base = (char*)d_ws;
    bf16_t* Wb     = (bf16_t*)(base);
    bf16_t* w_inp  = Wb;
    bf16_t* w_xp   = Wb + 4194304;
    bf16_t* w_dtp  = Wb + 4390912;
    bf16_t* w_outp = Wb + 4521984;
    bf16_t* w_f1   = Wb + 6619136;
    bf16_t* w_f2   = Wb + 10813440;

    bf16_t* h1b    = (bf16_t*)(base + 30015488);
    float*  proj   = (float*)(base + 30015488);           // alias (h1b dead)
    bf16_t* projdt = (bf16_t*)(base + 30015488 + 786432);
    bf16_t* xz     = (bf16_t*)(base + 34209792);          // 16 MB; ffnh later
    bf16_t* ffnh   = xz;
    bf16_t* xc     = (bf16_t*)(base + 50987008);          // 8 MB
    float*  part   = (float*)(base + 59375616);           // 16 MB multi-use
    float*  delta  = part;                                //   fp32 after reduce4
    bf16_t* partb  = (bf16_t*)part;                       //   bf16 splitK partials
    float*  carry  = (float*)(base + 76152832);           // 8 MB; nbufb later
    bf16_t* nbufb  = (bf16_t*)carry;
    float*  sumd   = (float*)(base + 84541440);
    float*  hinit  = (float*)(base + 85065728);           // 8 MB; nbuf later
    float*  nbuf   = hinit;
    bf16_t* yact   = (bf16_t*)(base + 93454336);          // 8 MB
    float*  hres   = (float*)(base + 101842944);          // 8 MB

    // 0. weights -> bf16
    cvt_weights<<<14656, 256, 0, stream>>>(in_proj, x_proj, dt_proj, out_proj,
                                           ffn_w1, ffn_w2, Wb);
    // 1. LN1 -> h1b (bf16)
    ln_kernel<0><<<L_SEQ, 256, 0, stream>>>(x, ln1_g, ln1_b, nullptr, h1b);
    // 2. xz = h1 @ in_proj^T   (2048x4096x1024) -> bf16
    gemm_async<0, 1><<<dim3(32, 16, 1), 256, 0, stream>>>(
        h1b, DMODEL, w_inp, DMODEL, xz, 4096, 4096, 1024, 0, nullptr);
    // 3. conv + silu -> xc (bf16)
    conv_silu<<<(L_SEQ * DINNER) / 256, 256, 0, stream>>>(xz, conv_w, conv_b, xc);
    // 4. proj partials = xc @ x_proj^T  (2048x96x2048, split-K 16, fp32)
    gemm_async<0, 0><<<dim3(1, 16, 16), 256, 0, stream>>>(
        xc, DINNER, w_xp, DINNER, part, 96, 96, 128, 196608L, nullptr);
    // 5. reduce -> proj fp32 + projdt bf16
    reduce4<<<768, 256, 0, stream>>>(part, proj, projdt);
    // 6. delta = softplus(dt @ dt_proj^T + b)  (2048x2048x64)
    gemm_async<3, 0><<<dim3(16, 16, 1), 256, 0, stream>>>(
        projdt, DTRANK, w_dtp, DTRANK, delta, DINNER, DINNER, DTRANK, 0, dt_b);
    // 7-9. scan
    scan_pass1<<<dim3(NC, DINNER / 256), 256, 0, stream>>>(delta, xc, proj, A_log, carry, sumd);
    scan_pass2<<<(DINNER * DSTATE) / 256, 256, 0, stream>>>(A_log, carry, sumd, hinit);
    scan_pass3<<<dim3(NC, DINNER / 256), 256, 0, stream>>>(delta, xc, proj, A_log, hinit,
                                                           D_param, xz, yact);
    // 10. out_proj partials (2048x1024x2048, split-K 4, bf16 partials)
    gemm_async<0, 1><<<dim3(8, 16, 4), 256, 0, stream>>>(
        yact, DINNER, w_outp, DINNER, partb, DMODEL, DMODEL, 512, 2097152L, nullptr);
    // 11. hres = sum(partials) + x
    reduce9<<<2048, 256, 0, stream>>>(partb, x, hres);
    // 12. LN2 -> nbuf fp32 + nbufb bf16
    ln_kernel<1><<<L_SEQ, 256, 0, stream>>>(hres, ln2_g, ln2_b, nbuf, nbufb);
    // 13. ffnh = relu(nbuf @ w1^T + b1) -> bf16  (2048x4096x1024)
    gemm_async<2, 1><<<dim3(32, 16, 1), 256, 0, stream>>>(
        nbufb, DMODEL, w_f1, DMODEL, ffnh, NHID, NHID, 1024, 0, ffn_b1);
    // 14. ffn2 partials (2048x1024x4096, split-K 4, bf16 partials)
    gemm_async<0, 1><<<dim3(8, 16, 4), 256, 0, stream>>>(
        ffnh, NHID, w_f2, NHID, partb, DMODEL, DMODEL, 1024, 2097152L, nullptr);
    // 15. out = sum(partials) + b2 + hres + nbuf
    reduce12<<<2048, 256, 0, stream>>>(partb, ffn_b2, hres, nbuf, out);
}

// Round 4
// 371.565 us; speedup vs baseline: 3.3443x; 1.0202x over previous
//
#include <hip/hip_runtime.h>
#include <hip/hip_bf16.h>
#include <math.h>

#define L_SEQ 2048
#define DMODEL 1024
#define DINNER 2048
#define DSTATE 16
#define DTRANK 64
#define NHID 4096
#define NC 64
#define LC 32

typedef __bf16 bf16_t;
typedef __bf16 bf16x4 __attribute__((ext_vector_type(4)));
typedef __bf16 bf16x8 __attribute__((ext_vector_type(8)));
typedef float f32x4 __attribute__((ext_vector_type(4)));

// waitcnt imms: vmcnt(N) | expcnt=7 | lgkmcnt=15
#define WAIT_VM0 0x0F70
#define WAIT_VM4 0x0F74
#define WAIT_VM8 0x0F78

__device__ __forceinline__ void async_cp16(const bf16_t* g, bf16_t* l) {
    __builtin_amdgcn_global_load_lds(
        (const __attribute__((address_space(1))) void*)g,
        (__attribute__((address_space(3))) void*)l, 16, 0, 0);
}

// ---------------------------------------------------------------------------
// C = A(M,K)bf16 @ W(N,K)bf16^T, 128x128 tile, 4-stage pipelined
// global_load_lds staging, fine-grained vmcnt across raw s_barrier.
// SWZ==1: 32x16 grid remapped so each XCD (blockid%8) owns an 8x8 C-region
// (A+B touch ~4MB = one XCD L2) for L2 reuse.
// EPI: 0 none | 2 relu+bias | 3 softplus+bias.  OUTBF16: bf16 vs fp32 store.
// ---------------------------------------------------------------------------
template <int EPI, int OUTBF16, int SWZ>
__global__ __launch_bounds__(256) void gemm_async(
    const bf16_t* __restrict__ A, int lda,
    const bf16_t* __restrict__ W, int ldw,
    void* __restrict__ Cv, int ldc,
    int N, int Kslice, long cstride,
    const float* __restrict__ bias)
{
    __shared__ bf16_t As[4 * 4096];
    __shared__ bf16_t Ws[4 * 4096];

    const int tid  = threadIdx.x;
    const int lane = tid & 63;
    const int w    = tid >> 6;

    int bx = blockIdx.x, by = blockIdx.y;
    if (SWZ == 1) {   // grid must be 32x16
        int lid = by * 32 + bx;
        int r = lid & 7, i = lid >> 3;
        bx = (r & 3) * 8 + (i & 7);
        by = (r >> 2) * 8 + (i >> 3);
    }
    const int m0   = by * 128;
    const int n0   = bx * 128;
    const int kz   = blockIdx.z;
    const int k0   = kz * Kslice;

    // staging: wave w stages chunks {2w,2w+1} (rows 32w..32w+31) of A and W.
    const int p   = lane & 3;
    const int r0  = 2 * w * 16 + (lane >> 2);
    const int r1  = r0 + 16;
    const int dc0 = (p - ((r0 >> 1) & 3)) & 3;
    const int dc1 = (p - ((r1 >> 1) & 3)) & 3;

    const bf16_t* gA0 = A + (size_t)(m0 + r0) * lda + k0 + dc0 * 8;
    const bf16_t* gA1 = A + (size_t)(m0 + r1) * lda + k0 + dc1 * 8;
    int gn0 = n0 + r0; if (gn0 > N - 1) gn0 = N - 1;
    int gn1 = n0 + r1; if (gn1 > N - 1) gn1 = N - 1;
    const bf16_t* gW0 = W + (size_t)gn0 * ldw + k0 + dc0 * 8;
    const bf16_t* gW1 = W + (size_t)gn1 * ldw + k0 + dc1 * 8;

    const int lo0 = (2 * w) * 512;
    const int lo1 = lo0 + 512;

    const int wr   = w >> 1;
    const int wc   = w & 1;
    const int quad = lane >> 4;
    const int lr   = lane & 15;
    int offA[4], offW[4];
    #pragma unroll
    for (int i = 0; i < 4; ++i) {
        int ra = wr * 64 + i * 16 + lr;
        offA[i] = ra * 32 + (((quad + ((ra >> 1) & 3)) & 3) * 8);
        int rb = wc * 64 + i * 16 + lr;
        offW[i] = rb * 32 + (((quad + ((rb >> 1) & 3)) & 3) * 8);
    }

    const int niter = Kslice >> 5;

    #pragma unroll
    for (int j = 0; j < 3; ++j) {
        if (j < niter) {
            int sb = j * 4096;
            async_cp16(gA0, &As[sb + lo0]);
            async_cp16(gA1, &As[sb + lo1]);
            async_cp16(gW0, &Ws[sb + lo0]);
            async_cp16(gW1, &Ws[sb + lo1]);
            gA0 += 32; gA1 += 32; gW0 += 32; gW1 += 32;
        }
    }

    f32x4 acc[4][4] = {};
    for (int it = 0; it < niter; ++it) {
        if (it + 3 <= niter)      __builtin_amdgcn_s_waitcnt(WAIT_VM8);
        else if (it + 2 <= niter) __builtin_amdgcn_s_waitcnt(WAIT_VM4);
        else                      __builtin_amdgcn_s_waitcnt(WAIT_VM0);
        __builtin_amdgcn_s_barrier();
        asm volatile("" ::: "memory");

        if (it + 3 < niter) {
            int sb = ((it + 3) & 3) * 4096;
            async_cp16(gA0, &As[sb + lo0]);
            async_cp16(gA1, &As[sb + lo1]);
            async_cp16(gW0, &Ws[sb + lo0]);
            async_cp16(gW1, &Ws[sb + lo1]);
            gA0 += 32; gA1 += 32; gW0 += 32; gW1 += 32;
        }

        const int cb = (it & 3) * 4096;
        bf16x8 af[4], bw[4];
        #pragma unroll
        for (int i = 0; i < 4; ++i) af[i] = *(const bf16x8*)&As[cb + offA[i]];
        #pragma unroll
        for (int j = 0; j < 4; ++j) bw[j] = *(const bf16x8*)&Ws[cb + offW[j]];
        #pragma unroll
        for (int i = 0; i < 4; ++i)
            #pragma unroll
            for (int j = 0; j < 4; ++j)
                acc[i][j] = __builtin_amdgcn_mfma_f32_16x16x32_bf16(af[i], bw[j], acc[i][j], 0, 0, 0);
    }

    float*  Cf = (float*)Cv + (size_t)kz * cstride;
    bf16_t* Cb = (bf16_t*)Cv + (size_t)kz * cstride;
    #pragma unroll
    for (int i = 0; i < 4; ++i) {
        int row0 = m0 + wr * 64 + i * 16 + quad * 4;
        #pragma unroll
        for (int j = 0; j < 4; ++j) {
            int col = n0 + wc * 64 + j * 16 + lr;
            if (col < N) {
                float bv = (EPI == 2 || EPI == 3) ? bias[col] : 0.f;
                #pragma unroll
                for (int r = 0; r < 4; ++r) {
                    float v = acc[i][j][r];
                    if (EPI == 2) v = fmaxf(v + bv, 0.f);
                    else if (EPI == 3) {
                        float t = v + bv;
                        v = fmaxf(t, 0.f) + log1pf(__expf(-fabsf(t)));
                    }
                    size_t o = (size_t)(row0 + r) * ldc + col;
                    if (OUTBF16) Cb[o] = (bf16_t)v;
                    else         Cf[o] = v;
                }
            }
        }
    }
}

// ---------------------------------------------------------------------------
// fused: weights fp32->bf16 (blocks 0..14655) + LN1 (blocks 14656..16703)
// ---------------------------------------------------------------------------
__global__ __launch_bounds__(256) void cvt_ln1(
    const float* __restrict__ s0, const float* __restrict__ s1,
    const float* __restrict__ s2, const float* __restrict__ s3,
    const float* __restrict__ s4, const float* __restrict__ s5,
    bf16_t* __restrict__ dst,
    const float* __restrict__ x, const float* __restrict__ g,
    const float* __restrict__ b, bf16_t* __restrict__ outb)
{
    if (blockIdx.x < 14656) {
        int e = (blockIdx.x * 256 + threadIdx.x) * 4;
        const float* src; int local;
        if      (e < 4194304)  { src = s0; local = e; }
        else if (e < 4390912)  { src = s1; local = e - 4194304; }
        else if (e < 4521984)  { src = s2; local = e - 4390912; }
        else if (e < 6619136)  { src = s3; local = e - 4521984; }
        else if (e < 10813440) { src = s4; local = e - 6619136; }
        else                   { src = s5; local = e - 10813440; }
        float4 v = *(const float4*)(src + local);
        bf16x4 o;
        o[0] = (bf16_t)v.x; o[1] = (bf16_t)v.y; o[2] = (bf16_t)v.z; o[3] = (bf16_t)v.w;
        *(bf16x4*)(dst + e) = o;
        return;
    }
    const int row = blockIdx.x - 14656;
    const float* xr = x + (size_t)row * DMODEL;
    float v[4];
    float s = 0.f, sq = 0.f;
    #pragma unroll
    for (int i = 0; i < 4; ++i) {
        v[i] = xr[threadIdx.x + i * 256];
        s += v[i]; sq += v[i] * v[i];
    }
    #pragma unroll
    for (int off = 32; off > 0; off >>= 1) {
        s += __shfl_xor(s, off); sq += __shfl_xor(sq, off);
    }
    __shared__ float rs_[4], rq_[4];
    int w = threadIdx.x >> 6;
    if ((threadIdx.x & 63) == 0) { rs_[w] = s; rq_[w] = sq; }
    __syncthreads();
    s  = rs_[0] + rs_[1] + rs_[2] + rs_[3];
    sq = rq_[0] + rq_[1] + rq_[2] + rq_[3];
    float mu  = s * (1.f / DMODEL);
    float var = sq * (1.f / DMODEL) - mu * mu;
    float rsd = rsqrtf(var + 1e-5f);
    #pragma unroll
    for (int i = 0; i < 4; ++i) {
        int col = threadIdx.x + i * 256;
        outb[(size_t)row * DMODEL + col] = (bf16_t)((v[i] - mu) * rsd * g[col] + b[col]);
    }
}

// ---------------------------------------------------------------------------
__global__ __launch_bounds__(256) void conv_silu(
    const bf16_t* __restrict__ xz, const float* __restrict__ cw,
    const float* __restrict__ cb, bf16_t* __restrict__ xc)
{
    int gid = blockIdx.x * 256 + threadIdx.x;
    int c = gid & (DINNER - 1);
    int t = gid >> 11;
    float acc = cb[c];
    #pragma unroll
    for (int k = 0; k < 4; ++k) {
        int tt = t + k - 3;
        if (tt >= 0) acc += (float)xz[(size_t)tt * (2 * DINNER) + c] * cw[c * 4 + k];
    }
    float sig = 1.f / (1.f + __expf(-acc));
    xc[gid] = (bf16_t)(acc * sig);
}

// ---------------------------------------------------------------------------
__global__ __launch_bounds__(256) void scan_pass1(
    const bf16_t* __restrict__ delta, const bf16_t* __restrict__ xc,
    const float* __restrict__ proj, const float* __restrict__ A_log,
    float* __restrict__ carryH, float* __restrict__ sumd)
{
    const int c = blockIdx.x;
    const int d = blockIdx.y * 256 + threadIdx.x;
    const int t0 = c * LC;

    __shared__ float Bs[LC][DSTATE];
    for (int i = threadIdx.x; i < LC * DSTATE; i += 256) {
        int tt = i >> 4, s = i & 15;
        Bs[tt][s] = proj[(size_t)(t0 + tt) * 96 + DTRANK + s];
    }
    __syncthreads();

    float a[DSTATE], h[DSTATE];
    #pragma unroll
    for (int s = 0; s < DSTATE; ++s) {
        a[s] = -__expf(A_log[d * DSTATE + s]);
        h[s] = 0.f;
    }
    float sd = 0.f;
    for (int i = 0; i < LC; ++i) {
        int t = t0 + i;
        float dl = (float)delta[(size_t)t * DINNER + d];
        float x  = (float)xc[(size_t)t * DINNER + d];
        sd += dl;
        float dx = dl * x;
        #pragma unroll
        for (int s = 0; s < DSTATE; ++s)
            h[s] = h[s] * __expf(dl * a[s]) + dx * Bs[i][s];
    }
    #pragma unroll
    for (int s = 0; s < DSTATE; ++s)
        carryH[((size_t)c * DINNER + d) * DSTATE + s] = h[s];
    sumd[c * DINNER + d] = sd;
}

// batched-prefetch chunk-carry combine: 8 independent loads per batch
__global__ __launch_bounds__(256) void scan_pass2(
    const float* __restrict__ A_log, const float* __restrict__ carryH,
    const float* __restrict__ sumd, float* __restrict__ hinit)
{
    int idx = blockIdx.x * 256 + threadIdx.x;   // (d,s) in [0, 32768)
    int d = idx >> 4;
    float a = -__expf(A_log[idx]);
    float hc = 0.f;
    for (int c0 = 0; c0 < NC; c0 += 8) {
        float H[8], P[8];
        #pragma unroll
        for (int j = 0; j < 8; ++j) {
            H[j] = carryH[(size_t)(c0 + j) * (DINNER * DSTATE) + idx];
            P[j] = __expf(a * sumd[(c0 + j) * DINNER + d]);
        }
        #pragma unroll
        for (int j = 0; j < 8; ++j) {
            hinit[(size_t)(c0 + j) * (DINNER * DSTATE) + idx] = hc;
            hc = H[j] + P[j] * hc;
        }
    }
}

__global__ __launch_bounds__(256) void scan_pass3(
    const bf16_t* __restrict__ delta, const bf16_t* __restrict__ xc,
    const float* __restrict__ proj, const float* __restrict__ A_log,
    const float* __restrict__ hinit, const float* __restrict__ Dp,
    const bf16_t* __restrict__ xz, bf16_t* __restrict__ yact)
{
    const int c = blockIdx.x;
    const int d = blockIdx.y * 256 + threadIdx.x;
    const int t0 = c * LC;

    __shared__ float Bs[LC][DSTATE], Cs[LC][DSTATE];
    for (int i = threadIdx.x; i < LC * DSTATE; i += 256) {
        int tt = i >> 4, s = i & 15;
        size_t base = (size_t)(t0 + tt) * 96;
        Bs[tt][s] = proj[base + DTRANK + s];
        Cs[tt][s] = proj[base + DTRANK + DSTATE + s];
    }
    __syncthreads();

    float a[DSTATE], h[DSTATE];
    #pragma unroll
    for (int s = 0; s < DSTATE; ++s) {
        a[s] = -__expf(A_log[d * DSTATE + s]);
        h[s] = hinit[(size_t)c * (DINNER * DSTATE) + d * DSTATE + s];
    }
    float DD = Dp[d];
    for (int i = 0; i < LC; ++i) {
        int t = t0 + i;
        float dl = (float)delta[(size_t)t * DINNER + d];
        float x  = (float)xc[(size_t)t * DINNER + d];
        float dx = dl * x;
        float y = 0.f;
        #pragma unroll
        for (int s = 0; s < DSTATE; ++s) {
            h[s] = h[s] * __expf(dl * a[s]) + dx * Bs[i][s];
            y += h[s] * Cs[i][s];
        }
        float yv = y + x * DD;
        float z = (float)xz[(size_t)t * (2 * DINNER) + DINNER + d];
        float sil = z / (1.f + __expf(-z));
        yact[(size_t)t * DINNER + d] = (bf16_t)(yv * sil);
    }
}

// ---------------------------------------------------------------------------
__global__ __launch_bounds__(256) void reduce4(
    const float* __restrict__ part, float* __restrict__ proj,
    bf16_t* __restrict__ projdt)
{
    int i = blockIdx.x * 256 + threadIdx.x;      // 196608
    float v = 0.f;
    #pragma unroll
    for (int s = 0; s < 16; ++s) v += part[(size_t)s * 196608 + i];
    proj[i] = v;
    int row = i / 96;
    int col = i - row * 96;
    if (col < DTRANK) projdt[row * DTRANK + col] = (bf16_t)v;
}

// fused: hres = sum4(part) + x ; then LN2 on the row -> nbuf fp32 + bf16
__global__ __launch_bounds__(256) void red9_ln2(
    const bf16_t* __restrict__ part, const float* __restrict__ x,
    const float* __restrict__ g, const float* __restrict__ b,
    float* __restrict__ hres, float* __restrict__ nbuf,
    bf16_t* __restrict__ nbufb)
{
    const int row = blockIdx.x;
    const size_t base = (size_t)row * DMODEL;
    float v[4];
    float s = 0.f, sq = 0.f;
    #pragma unroll
    for (int i = 0; i < 4; ++i) {
        int col = threadIdx.x + i * 256;
        float acc = x[base + col];
        #pragma unroll
        for (int sl = 0; sl < 4; ++sl)
            acc += (float)part[(size_t)sl * 2097152 + base + col];
        hres[base + col] = acc;
        v[i] = acc; s += acc; sq += acc * acc;
    }
    #pragma unroll
    for (int off = 32; off > 0; off >>= 1) {
        s += __shfl_xor(s, off); sq += __shfl_xor(sq, off);
    }
    __shared__ float rs_[4], rq_[4];
    int w = threadIdx.x >> 6;
    if ((threadIdx.x & 63) == 0) { rs_[w] = s; rq_[w] = sq; }
    __syncthreads();
    s  = rs_[0] + rs_[1] + rs_[2] + rs_[3];
    sq = rq_[0] + rq_[1] + rq_[2] + rq_[3];
    float mu  = s * (1.f / DMODEL);
    float var = sq * (1.f / DMODEL) - mu * mu;
    float rsd = rsqrtf(var + 1e-5f);
    #pragma unroll
    for (int i = 0; i < 4; ++i) {
        int col = threadIdx.x + i * 256;
        float o = (v[i] - mu) * rsd * g[col] + b[col];
        nbuf[base + col] = o;
        nbufb[base + col] = (bf16_t)o;
    }
}

__global__ __launch_bounds__(256) void reduce12(
    const bf16_t* __restrict__ part, const float* __restrict__ b2,
    const float* __restrict__ hres, const float* __restrict__ nbuf,
    float* __restrict__ out)
{
    int i = (blockIdx.x * 256 + threadIdx.x) * 4;
    float4 bb = *(const float4*)(b2 + (i & (DMODEL - 1)));
    float4 h  = *(const float4*)(hres + i);
    float4 n  = *(const float4*)(nbuf + i);
    float s0 = bb.x + h.x + n.x, s1 = bb.y + h.y + n.y;
    float s2 = bb.z + h.z + n.z, s3 = bb.w + h.w + n.w;
    #pragma unroll
    for (int sl = 0; sl < 4; ++sl) {
        bf16x4 v = *(const bf16x4*)(part + (size_t)sl * 2097152 + i);
        s0 += (float)v[0]; s1 += (float)v[1]; s2 += (float)v[2]; s3 += (float)v[3];
    }
    *(float4*)(out + i) = make_float4(s0, s1, s2, s3);
}

// ---------------------------------------------------------------------------
extern "C" void kernel_launch(void* const* d_in, const int* in_sizes, int n_in,
                              void* d_out, int out_size, void* d_ws, size_t ws_size,
                              hipStream_t stream)
{
    const float* x        = (const float*)d_in[0];
    const float* ln1_g    = (const float*)d_in[1];
    const float* ln1_b    = (const float*)d_in[2];
    const float* ln2_g    = (const float*)d_in[3];
    const float* ln2_b    = (const float*)d_in[4];
    const float* in_proj  = (const float*)d_in[5];
    const float* conv_w   = (const float*)d_in[6];
    const float* conv_b   = (const float*)d_in[7];
    const float* x_proj   = (const float*)d_in[8];
    const float* dt_proj  = (const float*)d_in[9];
    const float* dt_b     = (const float*)d_in[10];
    const float* A_log    = (const float*)d_in[11];
    const float* D_param  = (const float*)d_in[12];
    const float* out_proj = (const float*)d_in[13];
    const float* ffn_w1   = (const float*)d_in[14];
    const float* ffn_b1   = (const float*)d_in[15];
    const float* ffn_w2   = (const float*)d_in[16];
    const float* ffn_b2   = (const float*)d_in[17];
    float* out = (float*)d_out;

    char* base = (char*)d_ws;
    bf16_t* Wb     = (bf16_t*)(base);
    bf16_t* w_inp  = Wb;
    bf16_t* w_xp   = Wb + 4194304;
    bf16_t* w_dtp  = Wb + 4390912;
    bf16_t* w_outp = Wb + 4521984;
    bf16_t* w_f1   = Wb + 6619136;
    bf16_t* w_f2   = Wb + 10813440;

    bf16_t* h1b    = (bf16_t*)(base + 30015488);
    float*  proj   = (float*)(base + 30015488);           // alias (h1b dead)
    bf16_t* projdt = (bf16_t*)(base + 30015488 + 786432);
    bf16_t* xz     = (bf16_t*)(base + 34209792);          // 16 MB; ffnh later
    bf16_t* ffnh   = xz;
    bf16_t* xc     = (bf16_t*)(base + 50987008);          // 8 MB
    float*  part   = (float*)(base + 59375616);           // 16 MB multi-use
    bf16_t* delta  = (bf16_t*)part;                       //   bf16 after reduce4
    bf16_t* partb  = (bf16_t*)part;                       //   bf16 splitK partials
    float*  carry  = (float*)(base + 76152832);           // 8 MB; nbufb later
    bf16_t* nbufb  = (bf16_t*)carry;
    float*  sumd   = (float*)(base + 84541440);
    float*  hinit  = (float*)(base + 85065728);           // 8 MB; nbuf later
    float*  nbuf   = hinit;
    bf16_t* yact   = (bf16_t*)(base + 93454336);          // 8 MB
    float*  hres   = (float*)(base + 101842944);          // 8 MB

    // 1. weights->bf16 + LN1 (fused)
    cvt_ln1<<<14656 + 2048, 256, 0, stream>>>(in_proj, x_proj, dt_proj, out_proj,
                                              ffn_w1, ffn_w2, Wb,
                                              x, ln1_g, ln1_b, h1b);
    // 2. xz = h1 @ in_proj^T   (2048x4096x1024) -> bf16, XCD swizzle
    gemm_async<0, 1, 1><<<dim3(32, 16, 1), 256, 0, stream>>>(
        h1b, DMODEL, w_inp, DMODEL, xz, 4096, 4096, 1024, 0, nullptr);
    // 3. conv + silu -> xc (bf16)
    conv_silu<<<(L_SEQ * DINNER) / 256, 256, 0, stream>>>(xz, conv_w, conv_b, xc);
    // 4. proj partials = xc @ x_proj^T  (2048x96x2048, split-K 16, fp32)
    gemm_async<0, 0, 0><<<dim3(1, 16, 16), 256, 0, stream>>>(
        xc, DINNER, w_xp, DINNER, part, 96, 96, 128, 196608L, nullptr);
    // 5. reduce -> proj fp32 + projdt bf16
    reduce4<<<768, 256, 0, stream>>>(part, proj, projdt);
    // 6. delta = softplus(dt @ dt_proj^T + b)  (2048x2048x64) -> bf16
    gemm_async<3, 1, 0><<<dim3(16, 16, 1), 256, 0, stream>>>(
        projdt, DTRANK, w_dtp, DTRANK, delta, DINNER, DINNER, DTRANK, 0, dt_b);
    // 7-9. scan
    scan_pass1<<<dim3(NC, DINNER / 256), 256, 0, stream>>>(delta, xc, proj, A_log, carry, sumd);
    scan_pass2<<<(DINNER * DSTATE) / 256, 256, 0, stream>>>(A_log, carry, sumd, hinit);
    scan_pass3<<<dim3(NC, DINNER / 256), 256, 0, stream>>>(delta, xc, proj, A_log, hinit,
                                                           D_param, xz, yact);
    // 10. out_proj partials (2048x1024x2048, split-K 4, bf16 partials)
    gemm_async<0, 1, 0><<<dim3(8, 16, 4), 256, 0, stream>>>(
        yact, DINNER, w_outp, DINNER, partb, DMODEL, DMODEL, 512, 2097152L, nullptr);
    // 11. hres = sum(partials)+x ; LN2 -> nbuf fp32 + nbufb bf16 (fused)
    red9_ln2<<<L_SEQ, 256, 0, stream>>>(partb, x, ln2_g, ln2_b, hres, nbuf, nbufb);
    // 12. ffnh = relu(nbuf @ w1^T + b1) -> bf16  (2048x4096x1024), XCD swizzle
    gemm_async<2, 1, 1><<<dim3(32, 16, 1), 256, 0, stream>>>(
        nbufb, DMODEL, w_f1, DMODEL, ffnh, NHID, NHID, 1024, 0, ffn_b1);
    // 13. ffn2 partials (2048x1024x4096, split-K 4, bf16 partials)
    gemm_async<0, 1, 0><<<dim3(8, 16, 4), 256, 0, stream>>>(
        ffnh, NHID, w_f2, NHID, partb, DMODEL, DMODEL, 1024, 2097152L, nullptr);
    // 14. out = sum(partials) + b2 + hres + nbuf
    reduce12<<<2048, 256, 0, stream>>>(partb, ffn_b2, hres, nbuf, out);
}